// Round 12
// baseline (178.376 us; speedup 1.0000x reference)
//
#include <hip/hip_runtime.h>
#include <hip/hip_bf16.h>

// B=512, I=1152, K=8, L=16, O=7; IK=9216, LO=112.
// MFMA routing, bf16 inputs / fp32 accumulate, 6 dispatches:
//   prep0: x->xbf,xT (bf16) + wcTp0 = bf16(w/1152) padded + Z init   (once)
//   sq_gemm: s = xbf . wcTp with in-block 16-way K-split + LDS reduce,
//            then Z-divide + squash (separable by l via n=l*8+o padding)
//            -> vT bf16 (+out fp32 last iter).  256 blocks x 1024 thr.
//   g_wc: G = xT.vT (MFMA) -> w-contract -> block-local bij -> exp -> Z
//         -> padded wcTp tile build.  144 blocks x 512 thr.
// Softmax deferred: wcTp carries unnormalized exp, sq_gemm divides by Z_l.
// wcTp pad rows (o==7) are exact zeros -> s[pad]=0, sq-sum unaffected.
// Iter 3's bij update is dead code -> skipped. Only 16 atomics/block (Z).

#define NB 512
#define NI 1152
#define NLO 112
#define NIK 9216
#define NPAD 128             // padded N: n = l*8+o, o==7 is zero pad

typedef __attribute__((ext_vector_type(8))) short bf16x8;
typedef __attribute__((ext_vector_type(4))) float f32x4;

__device__ __forceinline__ ushort f2bf(float f) {
    __hip_bfloat16 h = __float2bfloat16(f);
    return *(ushort*)&h;
}

// ---- conv_x body: x fp32 -> xbf [b][ik] and xT [ik][b], both bf16 ----
__device__ __forceinline__ void conv_x_body(const float* __restrict__ x,
                                            ushort* __restrict__ xbf,
                                            ushort* __restrict__ xT, int bid) {
    __shared__ ushort tile[64][68];
    int kg = bid % 144, bg = bid / 144;
    int k0 = kg * 64, b0 = bg * 64;
    int t = threadIdx.x;
    for (int e = t; e < 1024; e += 256) {
        int r = e >> 4, c4 = (e & 15) * 4;
        float4 f = *(const float4*)&x[(size_t)(b0 + r) * NIK + k0 + c4];
        ushort4 u = { f2bf(f.x), f2bf(f.y), f2bf(f.z), f2bf(f.w) };
        *(ushort4*)&xbf[(size_t)(b0 + r) * NIK + k0 + c4] = u;
        tile[r][c4] = u.x; tile[r][c4 + 1] = u.y; tile[r][c4 + 2] = u.z; tile[r][c4 + 3] = u.w;
    }
    __syncthreads();
    for (int e = t; e < 1024; e += 256) {
        int kr = e >> 4, c4 = (e & 15) * 4;
        ushort4 u = { tile[c4][kr], tile[c4 + 1][kr], tile[c4 + 2][kr], tile[c4 + 3][kr] };
        *(ushort4*)&xT[(size_t)(k0 + kr) * NB + b0 + c4] = u;
    }
}

// ---- prep0: conv_x (0..1151) + iter0 padded wcTp = w/1152 (1152..1295) + Z init ----
__global__ __launch_bounds__(256) void prep0(const float* __restrict__ x,
                                             ushort* __restrict__ xbf,
                                             ushort* __restrict__ xT,
                                             const float* __restrict__ w,
                                             ushort* __restrict__ wcTp,
                                             float* __restrict__ Z) {
    if (blockIdx.x < 1152) { conv_x_body(x, xbf, xT, blockIdx.x); return; }
    __shared__ ushort tile[NPAD][66];
    int t = threadIdx.x;
    int ik0 = (blockIdx.x - 1152) * 64;
    if (blockIdx.x == 1152 && t < 48) Z[t] = (t < 16) ? 1.0f : 0.0f;
    const float cv = 1.0f / 1152.0f;
    for (int e = t; e < 8192; e += 256) {
        int ikl = e >> 7, np = e & 127;
        int l = np >> 3, o = np & 7;
        float wv = (o < 7) ? w[(size_t)(ik0 + ikl) * NLO + l * 7 + o] : 0.f;
        tile[np][ikl] = f2bf(cv * wv);
    }
    __syncthreads();
    for (int e = t; e < 8192; e += 256) {
        int np = e >> 6, ikl = e & 63;
        wcTp[(size_t)np * NIK + ik0 + ikl] = tile[np][ikl];
    }
}

// ---- sq_gemm: fused s-GEMM (in-block K-split) + Z-divide + squash -> vT/out ----
// 256 blocks = 32 M-tiles (bid&31, XCD-colocated per M) x 8 n-tiles; 16 waves.
__global__ __launch_bounds__(1024) void sq_gemm(const ushort* __restrict__ xbf,
                                                const ushort* __restrict__ wcTp,
                                                const float* __restrict__ Zit,
                                                ushort* __restrict__ vT,
                                                float* __restrict__ out, int wout) {
    __shared__ float sp[16][16][16];   // [wave][m][n] 16 KB
    __shared__ float ss[16][16];
    __shared__ float facs[16][2];
    __shared__ float zi[2];
    int bid = blockIdx.x;
    int mt = bid & 31, ng = bid >> 5;
    int b0 = mt * 16, n0 = ng * 16;
    int t = threadIdx.x;
    int wv = t >> 6, lane = t & 63;
    int row = lane & 15, quad = lane >> 4;
    int k0 = wv * 576;                 // 16-way K-split of 9216
    const ushort* ap = xbf + (size_t)(b0 + row) * NIK + k0 + quad * 8;
    const ushort* bp = wcTp + (size_t)(n0 + row) * NIK + k0 + quad * 8;
    f32x4 acc = {0.f, 0.f, 0.f, 0.f};
    #pragma unroll 6
    for (int ks = 0; ks < 18; ++ks) {  // 576/32
        bf16x8 a = *(const bf16x8*)(ap + ks * 32);
        bf16x8 b = *(const bf16x8*)(bp + ks * 32);
        acc = __builtin_amdgcn_mfma_f32_16x16x32_bf16(a, b, acc, 0, 0, 0);
    }
    if (t < 2) zi[t] = 1.0f / Zit[ng * 2 + t];
    #pragma unroll
    for (int r = 0; r < 4; ++r) sp[wv][quad * 4 + r][row] = acc[r];
    __syncthreads();
    if (t < 256) {
        int m = t >> 4, n = t & 15;
        float sv = 0.f;
        #pragma unroll
        for (int w8 = 0; w8 < 16; ++w8) sv += sp[w8][m][n];
        ss[m][n] = sv * zi[n >> 3];
    }
    __syncthreads();
    if (t < 32) {
        int m = t >> 1, ll = t & 1;
        float sq = 0.f;
        #pragma unroll
        for (int o = 0; o < 8; ++o) { float e = ss[m][ll * 8 + o]; sq += e * e; }
        facs[m][ll] = sqrtf(sq) / (1.0f + sq);   // == (sq/(1+sq))/norm; pad adds 0
    }
    __syncthreads();
    if (t < 256) {
        int m = t >> 4, n = t & 15;
        int o = n & 7, lg = ng * 2 + (n >> 3);
        if (o < 7) {
            float vv = ss[m][n] * facs[m][n >> 3];
            vT[(size_t)(o * 16 + lg) * NB + b0 + m] = f2bf(vv);
            if (wout) out[(size_t)(b0 + m) * NLO + o * 16 + lg] = vv;
        }
    }
}

// ---- g_wc: fused G-MFMA + w-contraction + bij update + exp + Z + wcTp build ----
// 144 blocks x 512 threads (8 waves = 4 ik-tiles x 2 B-halves); block owns
// i = blockIdx.x*8 .. +7 exclusively -> plain bij r/w, no atomics except Z.
__global__ __launch_bounds__(512) void g_wc(const ushort* __restrict__ xT,
                                            const ushort* __restrict__ vT,
                                            const float* __restrict__ w,
                                            float* __restrict__ bij,
                                            ushort* __restrict__ wcTp,
                                            float* __restrict__ Zit, int accum) {
    __shared__ float bs[2][8][16];
    __shared__ float cs[128];
    __shared__ ushort tile[NPAD][66];
    int t = threadIdx.x;
    int wv = t >> 6;                 // 0..7
    int lane = t & 63;
    int half = wv & 1;
    int mt = wv >> 1;                // 0..3
    int m0 = blockIdx.x * 64 + mt * 16;
    int kb0 = half * 256;
    int row = lane & 15, quad = lane >> 4;
    const ushort* ap = xT + (size_t)(m0 + row) * NB + kb0 + quad * 8;
    const ushort* bp = vT + (size_t)row * NB + kb0 + quad * 8;    // + nt*16*NB
    f32x4 acc[7];
    #pragma unroll
    for (int nt = 0; nt < 7; ++nt) acc[nt] = (f32x4){0.f, 0.f, 0.f, 0.f};
    #pragma unroll
    for (int ks = 0; ks < 8; ++ks) {                 // 256/32
        bf16x8 a = *(const bf16x8*)(ap + ks * 32);
        #pragma unroll
        for (int nt = 0; nt < 7; ++nt) {
            bf16x8 bfr = *(const bf16x8*)(bp + (size_t)nt * 16 * NB + ks * 32);
            acc[nt] = __builtin_amdgcn_mfma_f32_16x16x32_bf16(a, bfr, acc[nt], 0, 0, 0);
        }
    }
    // lane holds G[ik = m0+quad*4+r][o*16+l], o = nt, l = row
    float S = 0.f;
    #pragma unroll
    for (int r = 0; r < 4; ++r) {
        int ik = m0 + quad * 4 + r;
        const float* wr = w + (size_t)ik * NLO + row * 7;
        float p = 0.f;
        #pragma unroll
        for (int o = 0; o < 7; ++o) p += wr[o] * acc[o][r];
        S += p;
    }
    float Sp = __shfl_down(S, 16);                   // partner quad's 4-ik sum
    if ((quad & 1) == 0)
        bs[half][mt * 2 + (quad >> 1)][row] = (S + Sp) * (1.0f / 512.0f);
    __syncthreads();
    if (t < 128) {
        int il = t >> 4, l = t & 15;
        int i = blockIdx.x * 8 + il;
        float val = bs[0][il][l] + bs[1][il][l];
        if (accum) val += bij[i * 16 + l];
        bij[i * 16 + l] = val;
        cs[t] = expf(val);
    }
    __syncthreads();
    if (t < 16) {
        float z = 0.f;
        #pragma unroll
        for (int j = 0; j < 8; ++j) z += cs[j * 16 + t];
        atomicAdd(&Zit[t], z);
    }
    int ik0 = blockIdx.x * 64;
    for (int e = t; e < 8192; e += 512) {
        int ikl = e >> 7, np = e & 127;
        int l = np >> 3, o = np & 7;
        int il = ((ikl >> 3) << 4) + l;              // i_local*16 + l
        float wv_ = (o < 7) ? w[(size_t)(ik0 + ikl) * NLO + l * 7 + o] : 0.f;
        tile[np][ikl] = f2bf(cs[il] * wv_);
    }
    __syncthreads();
    for (int e = t; e < 8192; e += 512) {
        int np = e >> 6, ikl = e & 63;
        wcTp[(size_t)np * NIK + ik0 + ikl] = tile[np][ikl];
    }
}

extern "C" void kernel_launch(void* const* d_in, const int* in_sizes, int n_in,
                              void* d_out, int out_size, void* d_ws, size_t ws_size,
                              hipStream_t stream) {
    const float* x = (const float*)d_in[0];   // [512][9216]
    const float* w = (const float*)d_in[1];   // [9216][112]
    float* out = (float*)d_out;               // [512][112]
    float* ws = (float*)d_ws;
    float*  f_bij  = ws;                                  // 18432
    float*  f_Z    = f_bij + NI * 16;                     // 3*16
    ushort* xbf    = (ushort*)(f_Z + 48);                 // 512*9216
    ushort* xT     = xbf + (size_t)NB * NIK;              // 9216*512
    ushort* wcTp   = xT + (size_t)NIK * NB;               // 128*9216
    ushort* vT     = wcTp + (size_t)NPAD * NIK;           // 112*512
    prep0<<<1296, 256, 0, stream>>>(x, xbf, xT, w, wcTp, f_Z);
    for (int it = 0; it < 3; ++it) {
        sq_gemm<<<256, 1024, 0, stream>>>(xbf, wcTp, f_Z + it * 16, vT, out,
                                          it == 2 ? 1 : 0);
        if (it < 2)
            g_wc<<<144, 512, 0, stream>>>(xT, vT, w, f_bij, wcTp,
                                          f_Z + (it + 1) * 16, it);
    }
}

// Round 13
// 174.583 us; speedup vs baseline: 1.0217x; 1.0217x over previous
//
#include <hip/hip_runtime.h>
#include <hip/hip_bf16.h>

// B=512, I=1152, K=8, L=16, O=7; IK=9216, LO=112.
// MFMA routing, bf16 inputs / fp32 accumulate, 6 dispatches:
//   prep0: x->xbf,xT (bf16) + wpT = bf16(w) padded (STATIC) + eb0=1 + Z init
//   sq_gemm: s = xbf . (wpT scaled in-register by cs[i,l]=eb) with in-block
//            16-way K-split + LDS reduce, Z-divide + squash -> vT (+out last).
//            All GEMM operands static -> L2-resident across iters.
//   g_wc: G = xT.vT (MFMA) -> w-contract -> block-local bij -> eb=exp(bij) + Z
// Softmax deferred: fragments carry unnormalized exp, sq_gemm divides by Z_l.
// wpT pad rows (o==7) are exact zeros. Iter-3 bij update dead -> skipped.

#define NB 512
#define NI 1152
#define NLO 112
#define NIK 9216
#define NPAD 128             // padded N: n = l*8+o, o==7 is zero pad

typedef __attribute__((ext_vector_type(8))) short bf16x8;
typedef __attribute__((ext_vector_type(4))) float f32x4;

__device__ __forceinline__ ushort f2bf(float f) {
    __hip_bfloat16 h = __float2bfloat16(f);
    return *(ushort*)&h;
}
__device__ __forceinline__ float bf2f(short s) {
    union { unsigned int u; float f; } v;
    v.u = ((unsigned int)(unsigned short)s) << 16;
    return v.f;
}

// ---- conv_x body: x fp32 -> xbf [b][ik] and xT [ik][b], both bf16 ----
__device__ __forceinline__ void conv_x_body(const float* __restrict__ x,
                                            ushort* __restrict__ xbf,
                                            ushort* __restrict__ xT, int bid) {
    __shared__ ushort tile[64][68];
    int kg = bid % 144, bg = bid / 144;
    int k0 = kg * 64, b0 = bg * 64;
    int t = threadIdx.x;
    for (int e = t; e < 1024; e += 256) {
        int r = e >> 4, c4 = (e & 15) * 4;
        float4 f = *(const float4*)&x[(size_t)(b0 + r) * NIK + k0 + c4];
        ushort4 u = { f2bf(f.x), f2bf(f.y), f2bf(f.z), f2bf(f.w) };
        *(ushort4*)&xbf[(size_t)(b0 + r) * NIK + k0 + c4] = u;
        tile[r][c4] = u.x; tile[r][c4 + 1] = u.y; tile[r][c4 + 2] = u.z; tile[r][c4 + 3] = u.w;
    }
    __syncthreads();
    for (int e = t; e < 1024; e += 256) {
        int kr = e >> 4, c4 = (e & 15) * 4;
        ushort4 u = { tile[c4][kr], tile[c4 + 1][kr], tile[c4 + 2][kr], tile[c4 + 3][kr] };
        *(ushort4*)&xT[(size_t)(k0 + kr) * NB + b0 + c4] = u;
    }
}

// ---- prep0: conv_x (0..1151) + static wpT build + eb0=1 + Z init (1152..1295) ----
__global__ __launch_bounds__(256) void prep0(const float* __restrict__ x,
                                             ushort* __restrict__ xbf,
                                             ushort* __restrict__ xT,
                                             const float* __restrict__ w,
                                             ushort* __restrict__ wpT,
                                             float* __restrict__ eb,
                                             float* __restrict__ Z) {
    if (blockIdx.x < 1152) { conv_x_body(x, xbf, xT, blockIdx.x); return; }
    __shared__ ushort tile[NPAD][66];
    int t = threadIdx.x;
    int wb = blockIdx.x - 1152;      // 0..143
    int ik0 = wb * 64;
    if (blockIdx.x == 1152 && t < 48) Z[t] = (t < 16) ? 1152.0f : 0.0f;
    if (t < 128) eb[(size_t)(wb * 8 + (t >> 4)) * 16 + (t & 15)] = 1.0f;
    for (int e = t; e < 8192; e += 256) {
        int ikl = e >> 7, np = e & 127;
        int l = np >> 3, o = np & 7;
        float wv = (o < 7) ? w[(size_t)(ik0 + ikl) * NLO + l * 7 + o] : 0.f;
        tile[np][ikl] = f2bf(wv);
    }
    __syncthreads();
    for (int e = t; e < 8192; e += 256) {
        int np = e >> 6, ikl = e & 63;
        wpT[(size_t)np * NIK + ik0 + ikl] = tile[np][ikl];
    }
}

// ---- sq_gemm: fused s-GEMM (in-block K-split, B scaled by eb in-register)
//      + Z-divide + squash -> vT/out.  256 blocks x 1024 thr (16 waves). ----
// blocks sharing an xbf M-slice are bid%32-equal -> same XCD (bid%8 pattern).
__global__ __launch_bounds__(1024) void sq_gemm(const ushort* __restrict__ xbf,
                                                const ushort* __restrict__ wpT,
                                                const float* __restrict__ eb,
                                                const float* __restrict__ Zit,
                                                ushort* __restrict__ vT,
                                                float* __restrict__ out, int wout) {
    __shared__ float csl[NI * 2];      // [i][lsel] 9.2 KB
    __shared__ float sp[16][16][16];   // [wave][m][n] 16 KB
    __shared__ float ss[16][16];
    __shared__ float facs[16][2];
    __shared__ float zi[2];
    int bid = blockIdx.x;
    int mt = bid & 31, ng = bid >> 5;
    int b0 = mt * 16, n0 = ng * 16;
    int t = threadIdx.x;
    int wv = t >> 6, lane = t & 63;
    int row = lane & 15, quad = lane >> 4;
    int k0 = wv * 576;                 // 16-way K-split of 9216
    // stage this block's two l-columns of eb
    for (int e = t; e < NI * 2; e += 1024) {
        int i = e >> 1, ls = e & 1;
        csl[e] = eb[(size_t)i * 16 + ng * 2 + ls];
    }
    if (t < 2) zi[t] = 1.0f / Zit[ng * 2 + t];
    __syncthreads();
    const ushort* ap = xbf + (size_t)(b0 + row) * NIK + k0 + quad * 8;
    const ushort* bp = wpT + (size_t)(n0 + row) * NIK + k0 + quad * 8;
    int lsel = row >> 3;
    int i0 = (k0 >> 3) + quad;         // i of this lane's fragment at ks=0
    f32x4 acc = {0.f, 0.f, 0.f, 0.f};
    #pragma unroll 6
    for (int ks = 0; ks < 18; ++ks) {  // 576/32
        bf16x8 a = *(const bf16x8*)(ap + ks * 32);
        bf16x8 wf = *(const bf16x8*)(bp + ks * 32);
        float cv = csl[(i0 + ks * 4) * 2 + lsel];
        bf16x8 b;
        #pragma unroll
        for (int j = 0; j < 8; ++j) b[j] = (short)f2bf(bf2f(wf[j]) * cv);
        acc = __builtin_amdgcn_mfma_f32_16x16x32_bf16(a, b, acc, 0, 0, 0);
    }
    #pragma unroll
    for (int r = 0; r < 4; ++r) sp[wv][quad * 4 + r][row] = acc[r];
    __syncthreads();
    if (t < 256) {
        int m = t >> 4, n = t & 15;
        float sv = 0.f;
        #pragma unroll
        for (int w8 = 0; w8 < 16; ++w8) sv += sp[w8][m][n];
        ss[m][n] = sv * zi[n >> 3];
    }
    __syncthreads();
    if (t < 32) {
        int m = t >> 1, ll = t & 1;
        float sq = 0.f;
        #pragma unroll
        for (int o = 0; o < 8; ++o) { float e = ss[m][ll * 8 + o]; sq += e * e; }
        facs[m][ll] = sqrtf(sq) / (1.0f + sq);   // == (sq/(1+sq))/norm; pad adds 0
    }
    __syncthreads();
    if (t < 256) {
        int m = t >> 4, n = t & 15;
        int o = n & 7, lg = ng * 2 + (n >> 3);
        if (o < 7) {
            float vv = ss[m][n] * facs[m][n >> 3];
            vT[(size_t)(o * 16 + lg) * NB + b0 + m] = f2bf(vv);
            if (wout) out[(size_t)(b0 + m) * NLO + o * 16 + lg] = vv;
        }
    }
}

// ---- g_wc: G-MFMA + w-contraction + block-local bij update + eb=exp + Z ----
// 144 blocks x 512 threads (8 waves = 4 ik-tiles x 2 B-halves); block owns
// i = blockIdx.x*8 .. +7 exclusively -> plain bij/eb writes, atomics only on Z.
__global__ __launch_bounds__(512) void g_wc(const ushort* __restrict__ xT,
                                            const ushort* __restrict__ vT,
                                            const float* __restrict__ w,
                                            float* __restrict__ bij,
                                            float* __restrict__ eb,
                                            float* __restrict__ Zit, int accum) {
    __shared__ float bs[2][8][16];
    __shared__ float cs[128];
    int t = threadIdx.x;
    int wv = t >> 6;                 // 0..7
    int lane = t & 63;
    int half = wv & 1;
    int mt = wv >> 1;                // 0..3
    int m0 = blockIdx.x * 64 + mt * 16;
    int kb0 = half * 256;
    int row = lane & 15, quad = lane >> 4;
    const ushort* ap = xT + (size_t)(m0 + row) * NB + kb0 + quad * 8;
    const ushort* bp = vT + (size_t)row * NB + kb0 + quad * 8;    // + nt*16*NB
    f32x4 acc[7];
    #pragma unroll
    for (int nt = 0; nt < 7; ++nt) acc[nt] = (f32x4){0.f, 0.f, 0.f, 0.f};
    #pragma unroll
    for (int ks = 0; ks < 8; ++ks) {                 // 256/32
        bf16x8 a = *(const bf16x8*)(ap + ks * 32);
        #pragma unroll
        for (int nt = 0; nt < 7; ++nt) {
            bf16x8 bfr = *(const bf16x8*)(bp + (size_t)nt * 16 * NB + ks * 32);
            acc[nt] = __builtin_amdgcn_mfma_f32_16x16x32_bf16(a, bfr, acc[nt], 0, 0, 0);
        }
    }
    // lane holds G[ik = m0+quad*4+r][o*16+l], o = nt, l = row
    float S = 0.f;
    #pragma unroll
    for (int r = 0; r < 4; ++r) {
        int ik = m0 + quad * 4 + r;
        const float* wr = w + (size_t)ik * NLO + row * 7;
        float p = 0.f;
        #pragma unroll
        for (int o = 0; o < 7; ++o) p += wr[o] * acc[o][r];
        S += p;
    }
    float Sp = __shfl_down(S, 16);                   // partner quad's 4-ik sum
    if ((quad & 1) == 0)
        bs[half][mt * 2 + (quad >> 1)][row] = (S + Sp) * (1.0f / 512.0f);
    __syncthreads();
    if (t < 128) {
        int il = t >> 4, l = t & 15;
        int i = blockIdx.x * 8 + il;
        float val = bs[0][il][l] + bs[1][il][l];
        if (accum) val += bij[i * 16 + l];
        bij[i * 16 + l] = val;
        float e = expf(val);
        cs[t] = e;
        eb[(size_t)i * 16 + l] = e;
    }
    __syncthreads();
    if (t < 16) {
        float z = 0.f;
        #pragma unroll
        for (int j = 0; j < 8; ++j) z += cs[j * 16 + t];
        atomicAdd(&Zit[t], z);
    }
}

extern "C" void kernel_launch(void* const* d_in, const int* in_sizes, int n_in,
                              void* d_out, int out_size, void* d_ws, size_t ws_size,
                              hipStream_t stream) {
    const float* x = (const float*)d_in[0];   // [512][9216]
    const float* w = (const float*)d_in[1];   // [9216][112]
    float* out = (float*)d_out;               // [512][112]
    float* ws = (float*)d_ws;
    float*  f_bij  = ws;                                  // 18432
    float*  f_eb   = f_bij + NI * 16;                     // 18432
    float*  f_Z    = f_eb + NI * 16;                      // 3*16
    ushort* xbf    = (ushort*)(f_Z + 48);                 // 512*9216
    ushort* xT     = xbf + (size_t)NB * NIK;              // 9216*512
    ushort* wpT    = xT + (size_t)NIK * NB;               // 128*9216
    ushort* vT     = wpT + (size_t)NPAD * NIK;            // 112*512
    prep0<<<1296, 256, 0, stream>>>(x, xbf, xT, w, wpT, f_eb, f_Z);
    for (int it = 0; it < 3; ++it) {
        sq_gemm<<<256, 1024, 0, stream>>>(xbf, wpT, f_eb, f_Z + it * 16, vT, out,
                                          it == 2 ? 1 : 0);
        if (it < 2)
            g_wc<<<144, 512, 0, stream>>>(xT, vT, w, f_bij, f_eb,
                                          f_Z + (it + 1) * 16, it);
    }
}